// Round 1
// baseline (357.890 us; speedup 1.0000x reference)
//
#include <hip/hip_runtime.h>

// MultiHeadAttention: B=2, S=2048, D=1024, H=16, HD=64, scores MULTIPLIED by 64.
// Pipeline: proj (split-fp16 3-term MFMA GEMM) -> vh transpose -> flash attention.
// Workspace layout (needs 48 MB): qh_hi, qh_lo, kh_hi, kh_lo, vh, vhT  (8 MB each)

typedef _Float16 half4 __attribute__((ext_vector_type(4)));
typedef _Float16 half8 __attribute__((ext_vector_type(8)));
typedef float floatx4 __attribute__((ext_vector_type(4)));

#define MFMA_F16(a, b, c) __builtin_amdgcn_mfma_f32_16x16x32_f16((a), (b), (c), 0, 0, 0)

constexpr int SEQ = 2048;
constexpr int DM = 1024;
constexpr int NH = 16;
constexpr int HD = 64;
// 64 * log2(e): fold score scale + base-2 conversion into Q projection
constexpr float QSCALE = 92.33248261689366f;

__device__ inline void split4(const float4 f, half4& h, half4& l) {
  h[0] = (_Float16)f.x; l[0] = (_Float16)(f.x - (float)h[0]);
  h[1] = (_Float16)f.y; l[1] = (_Float16)(f.y - (float)h[1]);
  h[2] = (_Float16)f.z; l[2] = (_Float16)(f.z - (float)h[2]);
  h[3] = (_Float16)f.w; l[3] = (_Float16)(f.w - (float)h[3]);
}

// ---------------- projection GEMM: y = x @ W^T ----------------
// x [4096,1024] f32, W [1024,1024] f32 (row = out-feature -> already B^T layout)
// z=0: Q (scaled by QSCALE, hi/lo out)  z=1: K (hi/lo out)  z=2: V (fp16 out)
// outputs in [b, h, s, hd] layout
__global__ __launch_bounds__(256) void proj_kernel(
    const float* __restrict__ q, const float* __restrict__ k, const float* __restrict__ v,
    const float* __restrict__ Wq, const float* __restrict__ Wk, const float* __restrict__ Wv,
    _Float16* __restrict__ qh_hi, _Float16* __restrict__ qh_lo,
    _Float16* __restrict__ kh_hi, _Float16* __restrict__ kh_lo,
    _Float16* __restrict__ vh)
{
  const int z = blockIdx.z;
  const float* __restrict__ x = (z == 0) ? q : (z == 1) ? k : v;
  const float* __restrict__ W = (z == 0) ? Wq : (z == 1) ? Wk : Wv;

  __shared__ __align__(16) _Float16 As[2][128][40];  // [hi/lo][m][k], pad 32->40
  __shared__ __align__(16) _Float16 Bs[2][128][40];  // [hi/lo][n][k]

  const int tid = threadIdx.x;
  const int bm = blockIdx.x;          // 0..31  (M=4096 / 128)
  const int bn = blockIdx.y;          // 0..7   (N=1024 / 128)
  const int lane = tid & 63;
  const int l15 = lane & 15;
  const int quad = lane >> 4;
  const int w = tid >> 6;
  const int wm = w >> 1;              // wave -> 64x64 quadrant
  const int wn = w & 1;

  floatx4 acc[4][4];
  #pragma unroll
  for (int mt = 0; mt < 4; mt++)
    #pragma unroll
    for (int nt = 0; nt < 4; nt++)
      acc[mt][nt] = (floatx4){0.f, 0.f, 0.f, 0.f};

  for (int kk = 0; kk < DM; kk += 32) {
    __syncthreads();
    #pragma unroll
    for (int i = 0; i < 4; i++) {
      int c = i * 256 + tid;          // 1024 float4-chunks = 128 rows x 8
      int row = c >> 3;
      int col = (c & 7) * 4;
      float4 fa = *(const float4*)(x + (size_t)(bm * 128 + row) * DM + kk + col);
      float4 fb = *(const float4*)(W + (size_t)(bn * 128 + row) * DM + kk + col);
      half4 ah, al, bh_, bl_;
      split4(fa, ah, al);
      split4(fb, bh_, bl_);
      *(half4*)&As[0][row][col] = ah;
      *(half4*)&As[1][row][col] = al;
      *(half4*)&Bs[0][row][col] = bh_;
      *(half4*)&Bs[1][row][col] = bl_;
    }
    __syncthreads();

    half8 a_h[4], a_l[4], b_h[4], b_l[4];
    #pragma unroll
    for (int t = 0; t < 4; t++) {
      a_h[t] = *(const half8*)&As[0][wm * 64 + t * 16 + l15][quad * 8];
      a_l[t] = *(const half8*)&As[1][wm * 64 + t * 16 + l15][quad * 8];
      b_h[t] = *(const half8*)&Bs[0][wn * 64 + t * 16 + l15][quad * 8];
      b_l[t] = *(const half8*)&Bs[1][wn * 64 + t * 16 + l15][quad * 8];
    }
    if (z == 2) {
      #pragma unroll
      for (int mt = 0; mt < 4; mt++)
        #pragma unroll
        for (int nt = 0; nt < 4; nt++)
          acc[mt][nt] = MFMA_F16(a_h[mt], b_h[nt], acc[mt][nt]);
    } else {
      #pragma unroll
      for (int mt = 0; mt < 4; mt++)
        #pragma unroll
        for (int nt = 0; nt < 4; nt++) {
          floatx4 t0 = MFMA_F16(a_h[mt], b_h[nt], acc[mt][nt]);
          t0 = MFMA_F16(a_h[mt], b_l[nt], t0);
          acc[mt][nt] = MFMA_F16(a_l[mt], b_h[nt], t0);
        }
    }
  }

  const float scale = (z == 0) ? QSCALE : 1.0f;
  #pragma unroll
  for (int mt = 0; mt < 4; mt++)
    #pragma unroll
    for (int nt = 0; nt < 4; nt++)
      #pragma unroll
      for (int r = 0; r < 4; r++) {
        int gm = bm * 128 + wm * 64 + mt * 16 + quad * 4 + r;   // (b,s)
        int gn = bn * 128 + wn * 64 + nt * 16 + l15;            // h*64+hd
        int b = gm >> 11, s = gm & 2047;
        int h = gn >> 6, hd = gn & 63;
        size_t idx = ((size_t)(b * NH + h) * SEQ + s) * HD + hd;
        float val = acc[mt][nt][r] * scale;
        if (z == 2) {
          vh[idx] = (_Float16)val;
        } else {
          _Float16 hi = (_Float16)val;
          _Float16 lo = (_Float16)(val - (float)hi);
          if (z == 0) { qh_hi[idx] = hi; qh_lo[idx] = lo; }
          else        { kh_hi[idx] = hi; kh_lo[idx] = lo; }
        }
      }
}

// ---------------- vh [b,h,s,64] -> vhT [b,h,64,s] ----------------
__global__ __launch_bounds__(256) void transpose_v(const _Float16* __restrict__ vh,
                                                   _Float16* __restrict__ vhT)
{
  __shared__ __align__(16) _Float16 T[128][72];
  const int bh = blockIdx.x;          // 0..31
  const int sc = blockIdx.y;          // 0..15 (s-chunks of 128)
  const int tid = threadIdx.x;
  const _Float16* src = vh + ((size_t)bh * SEQ + sc * 128) * HD;
  #pragma unroll
  for (int i = 0; i < 4; i++) {
    int c = i * 256 + tid;            // 1024 chunks of 8 halfs: 128 rows x 8
    int row = c >> 3, off = (c & 7) * 8;
    *(half8*)&T[row][off] = *(const half8*)(src + (size_t)row * HD + off);
  }
  __syncthreads();
  _Float16* dst = vhT + (size_t)bh * HD * SEQ + sc * 128;
  #pragma unroll
  for (int i = 0; i < 4; i++) {
    int c = i * 256 + tid;            // 1024 chunks: 64 rows x 16
    int hd = c >> 4, off = (c & 15) * 8;
    half8 vv;
    #pragma unroll
    for (int j = 0; j < 8; j++) vv[j] = T[off + j][hd];
    *(half8*)(dst + (size_t)hd * SEQ + off) = vv;
  }
}

// ---------------- flash attention ----------------
// grid (bh=32, qb=16); block 256 (4 waves); wave owns 32 q-rows; key tiles of 64
__global__ __launch_bounds__(256) void flash_kernel(
    const _Float16* __restrict__ qh_hi, const _Float16* __restrict__ qh_lo,
    const _Float16* __restrict__ kh_hi, const _Float16* __restrict__ kh_lo,
    const _Float16* __restrict__ vhT, float* __restrict__ out)
{
  __shared__ __align__(16) _Float16 Kh[64][72];
  __shared__ __align__(16) _Float16 Kl[64][72];
  __shared__ __align__(16) _Float16 Vt[64][72];     // [d][key]
  __shared__ __align__(16) _Float16 P[4][32][72];   // per-wave P tile

  const int bh = blockIdx.x;          // 0..31
  const int qb = blockIdx.y;          // 0..15
  const int tid = threadIdx.x;
  const int wq = tid >> 6;
  const int lane = tid & 63;
  const int l15 = lane & 15;
  const int quad = lane >> 4;

  const size_t bh_off = (size_t)bh * SEQ * HD;
  const int qrow0 = qb * 128 + wq * 32;

  // Q fragments from global (A layout: row=l15, k contiguous)
  half8 aq_h[2][2], aq_l[2][2];
  #pragma unroll
  for (int mt = 0; mt < 2; mt++) {
    const _Float16* qp_h = qh_hi + bh_off + (size_t)(qrow0 + mt * 16 + l15) * HD;
    const _Float16* qp_l = qh_lo + bh_off + (size_t)(qrow0 + mt * 16 + l15) * HD;
    #pragma unroll
    for (int kc = 0; kc < 2; kc++) {
      aq_h[mt][kc] = *(const half8*)(qp_h + kc * 32 + quad * 8);
      aq_l[mt][kc] = *(const half8*)(qp_l + kc * 32 + quad * 8);
    }
  }

  float mrow[2][4], lrow[2][4];
  floatx4 Oacc[2][4];
  #pragma unroll
  for (int mt = 0; mt < 2; mt++)
    #pragma unroll
    for (int r = 0; r < 4; r++) { mrow[mt][r] = -3.0e38f; lrow[mt][r] = 0.f; }
  #pragma unroll
  for (int mt = 0; mt < 2; mt++)
    #pragma unroll
    for (int nd = 0; nd < 4; nd++) Oacc[mt][nd] = (floatx4){0.f, 0.f, 0.f, 0.f};

  for (int kt = 0; kt < SEQ / 64; kt++) {
    const int kbase = kt * 64;
    __syncthreads();
    {
      const _Float16* sk_h = kh_hi + bh_off + (size_t)kbase * HD;
      const _Float16* sk_l = kh_lo + bh_off + (size_t)kbase * HD;
      const _Float16* sv   = vhT + (size_t)bh * HD * SEQ + kbase;
      #pragma unroll
      for (int i = 0; i < 2; i++) {
        int c = i * 256 + tid;        // 512 chunks: 64 rows x 8
        int row = c >> 3, off = (c & 7) * 8;
        *(half8*)&Kh[row][off] = *(const half8*)(sk_h + row * HD + off);
        *(half8*)&Kl[row][off] = *(const half8*)(sk_l + row * HD + off);
        *(half8*)&Vt[row][off] = *(const half8*)(sv + (size_t)row * SEQ + off);
      }
    }
    __syncthreads();

    // S = (scaled q) @ k^T   (3-term split fp16)
    floatx4 sacc[2][4];
    #pragma unroll
    for (int nt = 0; nt < 4; nt++) {
      half8 bh0 = *(const half8*)&Kh[nt * 16 + l15][quad * 8];
      half8 bh1 = *(const half8*)&Kh[nt * 16 + l15][32 + quad * 8];
      half8 bl0 = *(const half8*)&Kl[nt * 16 + l15][quad * 8];
      half8 bl1 = *(const half8*)&Kl[nt * 16 + l15][32 + quad * 8];
      #pragma unroll
      for (int mt = 0; mt < 2; mt++) {
        floatx4 s4 = (floatx4){0.f, 0.f, 0.f, 0.f};
        s4 = MFMA_F16(aq_h[mt][0], bh0, s4);
        s4 = MFMA_F16(aq_h[mt][1], bh1, s4);
        s4 = MFMA_F16(aq_h[mt][0], bl0, s4);
        s4 = MFMA_F16(aq_h[mt][1], bl1, s4);
        s4 = MFMA_F16(aq_l[mt][0], bh0, s4);
        s4 = MFMA_F16(aq_l[mt][1], bh1, s4);
        sacc[mt][nt] = s4;
      }
    }

    // online softmax (base-2 domain; scale already folded into Q)
    #pragma unroll
    for (int mt = 0; mt < 2; mt++) {
      float rmax[4], al[4], rsum[4];
      #pragma unroll
      for (int r = 0; r < 4; r++)
        rmax[r] = fmaxf(fmaxf(sacc[mt][0][r], sacc[mt][1][r]),
                        fmaxf(sacc[mt][2][r], sacc[mt][3][r]));
      #pragma unroll
      for (int off = 1; off < 16; off <<= 1)
        #pragma unroll
        for (int r = 0; r < 4; r++)
          rmax[r] = fmaxf(rmax[r], __shfl_xor(rmax[r], off, 64));
      #pragma unroll
      for (int r = 0; r < 4; r++) {
        float mnew = fmaxf(mrow[mt][r], rmax[r]);
        al[r] = exp2f(mrow[mt][r] - mnew);
        mrow[mt][r] = mnew;
        rsum[r] = 0.f;
      }
      #pragma unroll
      for (int nt = 0; nt < 4; nt++)
        #pragma unroll
        for (int r = 0; r < 4; r++) {
          float p = exp2f(sacc[mt][nt][r] - mrow[mt][r]);
          rsum[r] += p;
          P[wq][mt * 16 + quad * 4 + r][nt * 16 + l15] = (_Float16)p;
        }
      #pragma unroll
      for (int off = 1; off < 16; off <<= 1)
        #pragma unroll
        for (int r = 0; r < 4; r++)
          rsum[r] += __shfl_xor(rsum[r], off, 64);
      #pragma unroll
      for (int r = 0; r < 4; r++)
        lrow[mt][r] = lrow[mt][r] * al[r] + rsum[r];
      #pragma unroll
      for (int nd = 0; nd < 4; nd++)
        #pragma unroll
        for (int r = 0; r < 4; r++)
          Oacc[mt][nd][r] *= al[r];
    }
    __syncthreads();   // P LDS visibility (C/D layout -> A layout)

    // O += P @ V
    #pragma unroll
    for (int nd = 0; nd < 4; nd++) {
      half8 v0 = *(const half8*)&Vt[nd * 16 + l15][quad * 8];
      half8 v1 = *(const half8*)&Vt[nd * 16 + l15][32 + quad * 8];
      #pragma unroll
      for (int mt = 0; mt < 2; mt++) {
        half8 p0 = *(const half8*)&P[wq][mt * 16 + l15][quad * 8];
        half8 p1 = *(const half8*)&P[wq][mt * 16 + l15][32 + quad * 8];
        Oacc[mt][nd] = MFMA_F16(p0, v0, Oacc[mt][nd]);
        Oacc[mt][nd] = MFMA_F16(p1, v1, Oacc[mt][nd]);
      }
    }
  }

  // epilogue: out[b,s,h*64+hd] fp32
  const int b = bh >> 4, h = bh & 15;
  #pragma unroll
  for (int mt = 0; mt < 2; mt++) {
    float rinv[4];
    #pragma unroll
    for (int r = 0; r < 4; r++) rinv[r] = 1.0f / lrow[mt][r];
    #pragma unroll
    for (int nd = 0; nd < 4; nd++)
      #pragma unroll
      for (int r = 0; r < 4; r++) {
        int s = qb * 128 + wq * 32 + mt * 16 + quad * 4 + r;
        out[(size_t)(b * SEQ + s) * DM + h * HD + nd * 16 + l15] =
            Oacc[mt][nd][r] * rinv[r];
      }
  }
}

extern "C" void kernel_launch(void* const* d_in, const int* in_sizes, int n_in,
                              void* d_out, int out_size, void* d_ws, size_t ws_size,
                              hipStream_t stream) {
  const float* q  = (const float*)d_in[0];
  const float* k  = (const float*)d_in[1];
  const float* v  = (const float*)d_in[2];
  const float* Wq = (const float*)d_in[3];
  const float* Wk = (const float*)d_in[4];
  const float* Wv = (const float*)d_in[5];
  float* out = (float*)d_out;

  const size_t SZ = (size_t)2 * NH * SEQ * HD;  // 4,194,304 halfs = 8 MB
  _Float16* ws    = (_Float16*)d_ws;            // need 6*SZ halfs = 48 MB
  _Float16* qh_hi = ws + 0 * SZ;
  _Float16* qh_lo = ws + 1 * SZ;
  _Float16* kh_hi = ws + 2 * SZ;
  _Float16* kh_lo = ws + 3 * SZ;
  _Float16* vh    = ws + 4 * SZ;
  _Float16* vhT   = ws + 5 * SZ;

  proj_kernel<<<dim3(32, 8, 3), 256, 0, stream>>>(q, k, v, Wq, Wk, Wv,
                                                  qh_hi, qh_lo, kh_hi, kh_lo, vh);
  transpose_v<<<dim3(32, 16), 256, 0, stream>>>(vh, vhT);
  flash_kernel<<<dim3(32, 16), 256, 0, stream>>>(qh_hi, qh_lo, kh_hi, kh_lo, vhT, out);
}

// Round 2
// 326.180 us; speedup vs baseline: 1.0972x; 1.0972x over previous
//
#include <hip/hip_runtime.h>

// MultiHeadAttention: B=2, S=2048, D=1024, H=16, HD=64, scores MULTIPLIED by 64.
// Pipeline: proj (split-fp16 3-term MFMA GEMM) -> vh transpose -> flash attention.
// Flash uses S^T formulation: q lives on l15, softmax reduces in-lane + 2 shuffles,
// P stored transposed (wave-private, no barrier) feeding PV as B-operand.
// Workspace layout (needs 48 MB): qh_hi, qh_lo, kh_hi, kh_lo, vh, vhT  (8 MB each)

typedef _Float16 half4 __attribute__((ext_vector_type(4)));
typedef _Float16 half8 __attribute__((ext_vector_type(8)));
typedef float floatx4 __attribute__((ext_vector_type(4)));

#define MFMA_F16(a, b, c) __builtin_amdgcn_mfma_f32_16x16x32_f16((a), (b), (c), 0, 0, 0)

constexpr int SEQ = 2048;
constexpr int DM = 1024;
constexpr int NH = 16;
constexpr int HD = 64;
// 64 * log2(e): fold score scale + base-2 conversion into Q projection
constexpr float QSCALE = 92.33248261689366f;

__device__ inline void split4(const float4 f, half4& h, half4& l) {
  h[0] = (_Float16)f.x; l[0] = (_Float16)(f.x - (float)h[0]);
  h[1] = (_Float16)f.y; l[1] = (_Float16)(f.y - (float)h[1]);
  h[2] = (_Float16)f.z; l[2] = (_Float16)(f.z - (float)h[2]);
  h[3] = (_Float16)f.w; l[3] = (_Float16)(f.w - (float)h[3]);
}

// ---------------- projection GEMM: y = x @ W^T ----------------
__global__ __launch_bounds__(256) void proj_kernel(
    const float* __restrict__ q, const float* __restrict__ k, const float* __restrict__ v,
    const float* __restrict__ Wq, const float* __restrict__ Wk, const float* __restrict__ Wv,
    _Float16* __restrict__ qh_hi, _Float16* __restrict__ qh_lo,
    _Float16* __restrict__ kh_hi, _Float16* __restrict__ kh_lo,
    _Float16* __restrict__ vh)
{
  const int z = blockIdx.z;
  const float* __restrict__ x = (z == 0) ? q : (z == 1) ? k : v;
  const float* __restrict__ W = (z == 0) ? Wq : (z == 1) ? Wk : Wv;

  __shared__ __align__(16) _Float16 As[2][128][40];  // [hi/lo][m][k], pad 32->40
  __shared__ __align__(16) _Float16 Bs[2][128][40];  // [hi/lo][n][k]

  const int tid = threadIdx.x;
  const int bm = blockIdx.x;          // 0..31  (M=4096 / 128)
  const int bn = blockIdx.y;          // 0..7   (N=1024 / 128)
  const int lane = tid & 63;
  const int l15 = lane & 15;
  const int quad = lane >> 4;
  const int w = tid >> 6;
  const int wm = w >> 1;
  const int wn = w & 1;

  floatx4 acc[4][4];
  #pragma unroll
  for (int mt = 0; mt < 4; mt++)
    #pragma unroll
    for (int nt = 0; nt < 4; nt++)
      acc[mt][nt] = (floatx4){0.f, 0.f, 0.f, 0.f};

  for (int kk = 0; kk < DM; kk += 32) {
    __syncthreads();
    #pragma unroll
    for (int i = 0; i < 4; i++) {
      int c = i * 256 + tid;
      int row = c >> 3;
      int col = (c & 7) * 4;
      float4 fa = *(const float4*)(x + (size_t)(bm * 128 + row) * DM + kk + col);
      float4 fb = *(const float4*)(W + (size_t)(bn * 128 + row) * DM + kk + col);
      half4 ah, al, bh_, bl_;
      split4(fa, ah, al);
      split4(fb, bh_, bl_);
      *(half4*)&As[0][row][col] = ah;
      *(half4*)&As[1][row][col] = al;
      *(half4*)&Bs[0][row][col] = bh_;
      *(half4*)&Bs[1][row][col] = bl_;
    }
    __syncthreads();

    half8 a_h[4], a_l[4], b_h[4], b_l[4];
    #pragma unroll
    for (int t = 0; t < 4; t++) {
      a_h[t] = *(const half8*)&As[0][wm * 64 + t * 16 + l15][quad * 8];
      a_l[t] = *(const half8*)&As[1][wm * 64 + t * 16 + l15][quad * 8];
      b_h[t] = *(const half8*)&Bs[0][wn * 64 + t * 16 + l15][quad * 8];
      b_l[t] = *(const half8*)&Bs[1][wn * 64 + t * 16 + l15][quad * 8];
    }
    if (z == 2) {
      #pragma unroll
      for (int mt = 0; mt < 4; mt++)
        #pragma unroll
        for (int nt = 0; nt < 4; nt++)
          acc[mt][nt] = MFMA_F16(a_h[mt], b_h[nt], acc[mt][nt]);
    } else {
      #pragma unroll
      for (int mt = 0; mt < 4; mt++)
        #pragma unroll
        for (int nt = 0; nt < 4; nt++) {
          floatx4 t0 = MFMA_F16(a_h[mt], b_h[nt], acc[mt][nt]);
          t0 = MFMA_F16(a_h[mt], b_l[nt], t0);
          acc[mt][nt] = MFMA_F16(a_l[mt], b_h[nt], t0);
        }
    }
  }

  const float scale = (z == 0) ? QSCALE : 1.0f;
  #pragma unroll
  for (int mt = 0; mt < 4; mt++)
    #pragma unroll
    for (int nt = 0; nt < 4; nt++)
      #pragma unroll
      for (int r = 0; r < 4; r++) {
        int gm = bm * 128 + wm * 64 + mt * 16 + quad * 4 + r;   // (b,s)
        int gn = bn * 128 + wn * 64 + nt * 16 + l15;            // h*64+hd
        int b = gm >> 11, s = gm & 2047;
        int h = gn >> 6, hd = gn & 63;
        size_t idx = ((size_t)(b * NH + h) * SEQ + s) * HD + hd;
        float val = acc[mt][nt][r] * scale;
        if (z == 2) {
          vh[idx] = (_Float16)val;
        } else {
          _Float16 hi = (_Float16)val;
          _Float16 lo = (_Float16)(val - (float)hi);
          if (z == 0) { qh_hi[idx] = hi; qh_lo[idx] = lo; }
          else        { kh_hi[idx] = hi; kh_lo[idx] = lo; }
        }
      }
}

// ---------------- vh [b,h,s,64] -> vhT [b,h,64,s] ----------------
__global__ __launch_bounds__(256) void transpose_v(const _Float16* __restrict__ vh,
                                                   _Float16* __restrict__ vhT)
{
  __shared__ __align__(16) _Float16 T[128][72];
  const int bh = blockIdx.x;
  const int sc = blockIdx.y;
  const int tid = threadIdx.x;
  const _Float16* src = vh + ((size_t)bh * SEQ + sc * 128) * HD;
  #pragma unroll
  for (int i = 0; i < 4; i++) {
    int c = i * 256 + tid;
    int row = c >> 3, off = (c & 7) * 8;
    *(half8*)&T[row][off] = *(const half8*)(src + (size_t)row * HD + off);
  }
  __syncthreads();
  _Float16* dst = vhT + (size_t)bh * HD * SEQ + sc * 128;
  #pragma unroll
  for (int i = 0; i < 4; i++) {
    int c = i * 256 + tid;
    int hd = c >> 4, off = (c & 15) * 8;
    half8 vv;
    #pragma unroll
    for (int j = 0; j < 8; j++) vv[j] = T[off + j][hd];
    *(half8*)(dst + (size_t)hd * SEQ + off) = vv;
  }
}

// ---------------- flash attention (S^T formulation) ----------------
// grid (bh=32, qb=32); block 256 = 4 waves; wave owns 16 q-rows (q on l15).
// S^T = K·Q^T  (C: row=key=quad*4+r, col=q=l15)
// O^T = V^T·P^T (A=Vt[d][key], B=PT[key][q]; C: row=d, col=q)
__global__ __launch_bounds__(256, 4) void flash_kernel(
    const _Float16* __restrict__ qh_hi, const _Float16* __restrict__ qh_lo,
    const _Float16* __restrict__ kh_hi, const _Float16* __restrict__ kh_lo,
    const _Float16* __restrict__ vhT, float* __restrict__ out)
{
  __shared__ __align__(16) _Float16 Kh[64][72];
  __shared__ __align__(16) _Float16 Kl[64][72];
  __shared__ __align__(16) _Float16 Vt[64][72];     // [d][key]
  __shared__ __align__(16) _Float16 PT[4][64][18];  // per-wave P^T: [key][q], pad 16->18

  const int bh = blockIdx.x;          // 0..31
  const int qb = blockIdx.y;          // 0..31 (64 q-rows per block)
  const int tid = threadIdx.x;
  const int wq = tid >> 6;
  const int lane = tid & 63;
  const int l15 = lane & 15;
  const int quad = lane >> 4;

  const size_t bh_off = (size_t)bh * SEQ * HD;
  const int qrow0 = qb * 64 + wq * 16;

  // Q as B-operand fragments: lane holds n=q=l15, k=d=quad*8+j
  half8 bq_h[2], bq_l[2];
  {
    const _Float16* qp_h = qh_hi + bh_off + (size_t)(qrow0 + l15) * HD;
    const _Float16* qp_l = qh_lo + bh_off + (size_t)(qrow0 + l15) * HD;
    #pragma unroll
    for (int kc = 0; kc < 2; kc++) {
      bq_h[kc] = *(const half8*)(qp_h + kc * 32 + quad * 8);
      bq_l[kc] = *(const half8*)(qp_l + kc * 32 + quad * 8);
    }
  }

  float mrow = -3.0e38f, lrow = 0.f;
  floatx4 Oacc[4];
  #pragma unroll
  for (int nd = 0; nd < 4; nd++) Oacc[nd] = (floatx4){0.f, 0.f, 0.f, 0.f};

  for (int kt = 0; kt < SEQ / 64; kt++) {
    const int kbase = kt * 64;
    __syncthreads();
    {
      const _Float16* sk_h = kh_hi + bh_off + (size_t)kbase * HD;
      const _Float16* sk_l = kh_lo + bh_off + (size_t)kbase * HD;
      const _Float16* sv   = vhT + (size_t)bh * HD * SEQ + kbase;
      #pragma unroll
      for (int i = 0; i < 2; i++) {
        int c = i * 256 + tid;        // 512 chunks: 64 rows x 8
        int row = c >> 3, off = (c & 7) * 8;
        *(half8*)&Kh[row][off] = *(const half8*)(sk_h + row * HD + off);
        *(half8*)&Kl[row][off] = *(const half8*)(sk_l + row * HD + off);
        *(half8*)&Vt[row][off] = *(const half8*)(sv + (size_t)row * SEQ + off);
      }
    }
    __syncthreads();

    // S^T = K·Q^T  (3-term split fp16): sacc[nt] covers keys nt*16..nt*16+15
    floatx4 sacc[4];
    #pragma unroll
    for (int nt = 0; nt < 4; nt++) {
      half8 ak0 = *(const half8*)&Kh[nt * 16 + l15][quad * 8];
      half8 ak1 = *(const half8*)&Kh[nt * 16 + l15][32 + quad * 8];
      half8 am0 = *(const half8*)&Kl[nt * 16 + l15][quad * 8];
      half8 am1 = *(const half8*)&Kl[nt * 16 + l15][32 + quad * 8];
      floatx4 s4 = (floatx4){0.f, 0.f, 0.f, 0.f};
      s4 = MFMA_F16(ak0, bq_h[0], s4);
      s4 = MFMA_F16(ak1, bq_h[1], s4);
      s4 = MFMA_F16(ak0, bq_l[0], s4);
      s4 = MFMA_F16(ak1, bq_l[1], s4);
      s4 = MFMA_F16(am0, bq_h[0], s4);
      s4 = MFMA_F16(am1, bq_h[1], s4);
      sacc[nt] = s4;
    }

    // online softmax over keys: 15 in-lane max + 2 shuffles
    float rmax = sacc[0][0];
    #pragma unroll
    for (int nt = 0; nt < 4; nt++)
      #pragma unroll
      for (int r = 0; r < 4; r++) rmax = fmaxf(rmax, sacc[nt][r]);
    rmax = fmaxf(rmax, __shfl_xor(rmax, 16, 64));
    rmax = fmaxf(rmax, __shfl_xor(rmax, 32, 64));
    const float mnew = fmaxf(mrow, rmax);
    const float alpha = exp2f(mrow - mnew);
    mrow = mnew;

    float rsum = 0.f;
    #pragma unroll
    for (int nt = 0; nt < 4; nt++)
      #pragma unroll
      for (int r = 0; r < 4; r++) {
        float p = exp2f(sacc[nt][r] - mnew);
        rsum += p;
        PT[wq][nt * 16 + quad * 4 + r][l15] = (_Float16)p;  // wave-private
      }
    rsum += __shfl_xor(rsum, 16, 64);
    rsum += __shfl_xor(rsum, 32, 64);
    lrow = lrow * alpha + rsum;
    #pragma unroll
    for (int nd = 0; nd < 4; nd++) {
      Oacc[nd][0] *= alpha; Oacc[nd][1] *= alpha;
      Oacc[nd][2] *= alpha; Oacc[nd][3] *= alpha;
    }

    // O^T += V^T · P^T   (PT wave-private: in-order LDS pipe, no barrier)
    #pragma unroll
    for (int kc = 0; kc < 2; kc++) {
      half8 bp;
      #pragma unroll
      for (int j = 0; j < 8; j++)
        bp[j] = PT[wq][kc * 32 + quad * 8 + j][l15];
      #pragma unroll
      for (int nd = 0; nd < 4; nd++) {
        half8 av = *(const half8*)&Vt[nd * 16 + l15][kc * 32 + quad * 8];
        Oacc[nd] = MFMA_F16(av, bp, Oacc[nd]);
      }
    }
  }

  // epilogue: O^T C-layout -> out[b,s,h*64+d] fp32, float4 per nd
  const int b = bh >> 4, h = bh & 15;
  const int s = qb * 64 + wq * 16 + l15;
  const float rinv = 1.0f / lrow;
  float* obase = out + (size_t)(b * SEQ + s) * DM + h * HD;
  #pragma unroll
  for (int nd = 0; nd < 4; nd++) {
    float4 vv;
    vv.x = Oacc[nd][0] * rinv;
    vv.y = Oacc[nd][1] * rinv;
    vv.z = Oacc[nd][2] * rinv;
    vv.w = Oacc[nd][3] * rinv;
    *(float4*)(obase + nd * 16 + quad * 4) = vv;
  }
}

extern "C" void kernel_launch(void* const* d_in, const int* in_sizes, int n_in,
                              void* d_out, int out_size, void* d_ws, size_t ws_size,
                              hipStream_t stream) {
  const float* q  = (const float*)d_in[0];
  const float* k  = (const float*)d_in[1];
  const float* v  = (const float*)d_in[2];
  const float* Wq = (const float*)d_in[3];
  const float* Wk = (const float*)d_in[4];
  const float* Wv = (const float*)d_in[5];
  float* out = (float*)d_out;

  const size_t SZ = (size_t)2 * NH * SEQ * HD;  // 8 MB per array
  _Float16* ws    = (_Float16*)d_ws;            // 48 MB total
  _Float16* qh_hi = ws + 0 * SZ;
  _Float16* qh_lo = ws + 1 * SZ;
  _Float16* kh_hi = ws + 2 * SZ;
  _Float16* kh_lo = ws + 3 * SZ;
  _Float16* vh    = ws + 4 * SZ;
  _Float16* vhT   = ws + 5 * SZ;

  proj_kernel<<<dim3(32, 8, 3), 256, 0, stream>>>(q, k, v, Wq, Wk, Wv,
                                                  qh_hi, qh_lo, kh_hi, kh_lo, vh);
  transpose_v<<<dim3(32, 16), 256, 0, stream>>>(vh, vhT);
  flash_kernel<<<dim3(32, 32), 256, 0, stream>>>(qh_hi, qh_lo, kh_hi, kh_lo, vhT, out);
}